// Round 1
// baseline (485.855 us; speedup 1.0000x reference)
//
#include <hip/hip_runtime.h>
#include <hip/hip_bf16.h>

#define FIN 256
#define HID 128

// ---------------- degree count ----------------
__global__ void k_deg(const int* __restrict__ dst, int* __restrict__ deg, int e) {
    int i = blockIdx.x * blockDim.x + threadIdx.x;
    if (i < e) atomicAdd(&deg[dst[i]], 1);
}

// ---------------- 3-kernel exclusive scan over deg (n <= 512*256) ----------------
__global__ __launch_bounds__(256) void k_scan1(const int* __restrict__ deg, int* __restrict__ partial,
                                               int* __restrict__ bsum, int n) {
    __shared__ int sm[256];
    int t = threadIdx.x;
    int i = blockIdx.x * 256 + t;
    int v = (i < n) ? deg[i] : 0;
    sm[t] = v;
    __syncthreads();
    int acc = v;
    for (int off = 1; off < 256; off <<= 1) {
        int u = (t >= off) ? sm[t - off] : 0;
        __syncthreads();
        acc += u;
        sm[t] = acc;
        __syncthreads();
    }
    if (i < n) partial[i] = acc;      // inclusive within block
    if (t == 255) bsum[blockIdx.x] = acc;
}

__global__ __launch_bounds__(512) void k_scan2(const int* __restrict__ bsum, int* __restrict__ boff, int nb) {
    __shared__ int sm[512];
    int t = threadIdx.x;
    int v = (t < nb) ? bsum[t] : 0;
    sm[t] = v;
    __syncthreads();
    int acc = v;
    for (int off = 1; off < 512; off <<= 1) {
        int u = (t >= off) ? sm[t - off] : 0;
        __syncthreads();
        acc += u;
        sm[t] = acc;
        __syncthreads();
    }
    if (t < nb) boff[t] = acc - v;    // exclusive block offsets
}

__global__ __launch_bounds__(256) void k_scan3(const int* __restrict__ deg, const int* __restrict__ partial,
                                               const int* __restrict__ boff, int* __restrict__ rowptr,
                                               int* __restrict__ cursor, float* __restrict__ dinv,
                                               int n, int e) {
    int i = blockIdx.x * 256 + threadIdx.x;
    if (i >= n) return;
    int excl = boff[blockIdx.x] + partial[i] - deg[i];
    rowptr[i] = excl;
    cursor[i] = excl;
    dinv[i] = rsqrtf((float)(deg[i] + 1));   // +1 = self loop; always >= 1
    if (i == 0) rowptr[n] = e;
}

// ---------------- CSR fill (by dst) ----------------
__global__ void k_fill(const int* __restrict__ src, const int* __restrict__ dst,
                       int* __restrict__ cursor, int* __restrict__ csr_src, int e) {
    int i = blockIdx.x * blockDim.x + threadIdx.x;
    if (i < e) {
        int p = atomicAdd(&cursor[dst[i]], 1);
        csr_src[p] = src[i];
    }
}

// ---------------- GEMM1: hs[i][f] = dinv[i] * sum_k x[i][k]*W1[f][k] ----------------
// BM=32 nodes per block, BK=64, 256 threads, each thread 4x4 outputs.
#define BM 32
#define BK 64
__global__ __launch_bounds__(256) void k_gemm(const float* __restrict__ x, const float* __restrict__ W1,
                                              const float* __restrict__ dinv, float* __restrict__ hs, int n) {
    __shared__ float xs[BK][BM + 4];   // [kk][m], padded
    __shared__ float ws[BK][HID];      // [kk][f]
    const int tid = threadIdx.x;
    const int i0 = blockIdx.x * BM;
    const int m0 = (tid >> 5) << 2;    // 0..28
    const int f0 = (tid & 31) << 2;    // 0..124
    float acc[4][4] = {};

    for (int kb = 0; kb < FIN; kb += BK) {
        // stage x tile (32 rows x 64 k)
        {
            int r = tid >> 4;               // 0..15
            int c = (tid & 15) << 2;        // 0..60
            for (int rr = r; rr < BM; rr += 16) {
                int gi = i0 + rr;
                float4 v = {0.f, 0.f, 0.f, 0.f};
                if (gi < n) v = *(const float4*)&x[(size_t)gi * FIN + kb + c];
                xs[c + 0][rr] = v.x; xs[c + 1][rr] = v.y;
                xs[c + 2][rr] = v.z; xs[c + 3][rr] = v.w;
            }
        }
        // stage W tile (128 f x 64 k)
        {
            int f = tid >> 1;               // 0..127
            int c = (tid & 1) << 5;         // 0 or 32
            for (int j = 0; j < 32; j += 4) {
                float4 v = *(const float4*)&W1[(size_t)f * FIN + kb + c + j];
                ws[c + j + 0][f] = v.x; ws[c + j + 1][f] = v.y;
                ws[c + j + 2][f] = v.z; ws[c + j + 3][f] = v.w;
            }
        }
        __syncthreads();
        #pragma unroll
        for (int kk = 0; kk < BK; ++kk) {
            float4 a = *(const float4*)&xs[kk][m0];
            float4 b = *(const float4*)&ws[kk][f0];
            acc[0][0] += a.x * b.x; acc[0][1] += a.x * b.y; acc[0][2] += a.x * b.z; acc[0][3] += a.x * b.w;
            acc[1][0] += a.y * b.x; acc[1][1] += a.y * b.y; acc[1][2] += a.y * b.z; acc[1][3] += a.y * b.w;
            acc[2][0] += a.z * b.x; acc[2][1] += a.z * b.y; acc[2][2] += a.z * b.z; acc[2][3] += a.z * b.w;
            acc[3][0] += a.w * b.x; acc[3][1] += a.w * b.y; acc[3][2] += a.w * b.z; acc[3][3] += a.w * b.w;
        }
        __syncthreads();
    }
    #pragma unroll
    for (int i = 0; i < 4; ++i) {
        int gi = i0 + m0 + i;
        if (gi < n) {
            float di = dinv[gi];
            float4 o = {acc[i][0] * di, acc[i][1] * di, acc[i][2] * di, acc[i][3] * di};
            *(float4*)&hs[(size_t)gi * HID + f0] = o;
        }
    }
}

// ---------------- layer-1 aggregation fused with layer-2 dot ----------------
// one wave per node: acc(128) = hs[i] + sum_{in-edges} hs[src]; h1 = relu(acc*dinv+b1);
// zs[i] = dot(h1, W2) * dinv[i]
__global__ __launch_bounds__(256) void k_agg1(const float* __restrict__ hs, const int* __restrict__ rowptr,
                                              const int* __restrict__ csr_src, const float* __restrict__ dinv,
                                              const float* __restrict__ b1, const float* __restrict__ W2,
                                              float* __restrict__ zs, int n) {
    int i = (blockIdx.x << 2) + (threadIdx.x >> 6);
    if (i >= n) return;
    int lane = threadIdx.x & 63;
    float2 acc = *(const float2*)&hs[(size_t)i * HID + (lane << 1)];   // self loop term
    int beg = rowptr[i], end = rowptr[i + 1];
    for (int e = beg; e < end; ++e) {
        int s = csr_src[e];
        float2 v = *(const float2*)&hs[(size_t)s * HID + (lane << 1)];
        acc.x += v.x;
        acc.y += v.y;
    }
    float di = dinv[i];
    float2 bb = *(const float2*)&b1[lane << 1];
    float h0 = fmaxf(acc.x * di + bb.x, 0.f);
    float h1 = fmaxf(acc.y * di + bb.y, 0.f);
    float2 w2 = *(const float2*)&W2[lane << 1];
    float z = h0 * w2.x + h1 * w2.y;
    #pragma unroll
    for (int off = 32; off; off >>= 1) z += __shfl_xor(z, off, 64);
    if (lane == 0) zs[i] = z * di;
}

// ---------------- layer-2 aggregation ----------------
__global__ void k_agg2(const float* __restrict__ zs, const int* __restrict__ rowptr,
                       const int* __restrict__ csr_src, const float* __restrict__ dinv,
                       const float* __restrict__ b2, float* __restrict__ out, int n) {
    int i = blockIdx.x * blockDim.x + threadIdx.x;
    if (i >= n) return;
    float acc = zs[i];
    int beg = rowptr[i], end = rowptr[i + 1];
    for (int e = beg; e < end; ++e) acc += zs[csr_src[e]];
    out[i] = acc * dinv[i] + b2[0];
}

extern "C" void kernel_launch(void* const* d_in, const int* in_sizes, int n_in,
                              void* d_out, int out_size, void* d_ws, size_t ws_size,
                              hipStream_t stream) {
    const float* x  = (const float*)d_in[0];
    const int*   ei = (const int*)d_in[1];
    const float* W1 = (const float*)d_in[2];
    const float* b1 = (const float*)d_in[3];
    const float* W2 = (const float*)d_in[4];
    const float* b2 = (const float*)d_in[5];
    float* out = (float*)d_out;

    const int n = in_sizes[0] / FIN;
    const int e = in_sizes[1] / 2;
    const int* src = ei;
    const int* dst = ei + e;

    char* p = (char*)d_ws;
    auto carve = [&](size_t bytes) { char* q = p; p += (bytes + 255) & ~(size_t)255; return q; };
    int*   deg     = (int*)carve((size_t)n * 4);
    int*   partial = (int*)carve((size_t)n * 4);
    int*   bsum    = (int*)carve(4096);
    int*   boff    = (int*)carve(4096);
    int*   rowptr  = (int*)carve((size_t)(n + 1) * 4);
    int*   cursor  = (int*)carve((size_t)n * 4);
    float* dinv    = (float*)carve((size_t)n * 4);
    int*   csr     = (int*)carve((size_t)e * 4);
    float* hs      = (float*)carve((size_t)n * HID * 4);
    float* zs      = (float*)carve((size_t)n * 4);

    hipMemsetAsync(deg, 0, (size_t)n * 4, stream);

    const int nb = (n + 255) / 256;
    k_deg  <<<(e + 255) / 256, 256, 0, stream>>>(dst, deg, e);
    k_scan1<<<nb, 256, 0, stream>>>(deg, partial, bsum, n);
    k_scan2<<<1, 512, 0, stream>>>(bsum, boff, nb);
    k_scan3<<<nb, 256, 0, stream>>>(deg, partial, boff, rowptr, cursor, dinv, n, e);
    k_fill <<<(e + 255) / 256, 256, 0, stream>>>(src, dst, cursor, csr, e);
    k_gemm <<<(n + BM - 1) / BM, 256, 0, stream>>>(x, W1, dinv, hs, n);
    k_agg1 <<<(n + 3) / 4, 256, 0, stream>>>(hs, rowptr, csr, dinv, b1, W2, zs, n);
    k_agg2 <<<(n + 255) / 256, 256, 0, stream>>>(zs, rowptr, csr, dinv, b2, out, n);
}

// Round 2
// 397.741 us; speedup vs baseline: 1.2215x; 1.2215x over previous
//
#include <hip/hip_runtime.h>
#include <hip/hip_bf16.h>

#define FIN 256
#define HID 128

typedef __attribute__((ext_vector_type(8))) unsigned short ushort8v;

static __device__ __forceinline__ unsigned short f2bf(float f) {
    unsigned int u = __float_as_uint(f);
    u += 0x7fffu + ((u >> 16) & 1u);   // round-to-nearest-even
    return (unsigned short)(u >> 16);
}

// ---------------- degree count ----------------
__global__ void k_deg(const int* __restrict__ dst, int* __restrict__ deg, int e) {
    int i = blockIdx.x * blockDim.x + threadIdx.x;
    if (i < e) atomicAdd(&deg[dst[i]], 1);
}

// ---------------- 3-kernel exclusive scan over deg ----------------
__global__ __launch_bounds__(256) void k_scan1(const int* __restrict__ deg, int* __restrict__ partial,
                                               int* __restrict__ bsum, int n) {
    __shared__ int sm[256];
    int t = threadIdx.x;
    int i = blockIdx.x * 256 + t;
    int v = (i < n) ? deg[i] : 0;
    sm[t] = v;
    __syncthreads();
    int acc = v;
    for (int off = 1; off < 256; off <<= 1) {
        int u = (t >= off) ? sm[t - off] : 0;
        __syncthreads();
        acc += u;
        sm[t] = acc;
        __syncthreads();
    }
    if (i < n) partial[i] = acc;      // inclusive within block
    if (t == 255) bsum[blockIdx.x] = acc;
}

__global__ __launch_bounds__(512) void k_scan2(const int* __restrict__ bsum, int* __restrict__ boff, int nb) {
    __shared__ int sm[512];
    int t = threadIdx.x;
    int v = (t < nb) ? bsum[t] : 0;
    sm[t] = v;
    __syncthreads();
    int acc = v;
    for (int off = 1; off < 512; off <<= 1) {
        int u = (t >= off) ? sm[t - off] : 0;
        __syncthreads();
        acc += u;
        sm[t] = acc;
        __syncthreads();
    }
    if (t < nb) boff[t] = acc - v;    // exclusive block offsets
}

__global__ __launch_bounds__(256) void k_scan3(const int* __restrict__ deg, const int* __restrict__ partial,
                                               const int* __restrict__ boff, int* __restrict__ rowptr,
                                               int* __restrict__ cursor, float* __restrict__ dinv,
                                               int n, int e) {
    int i = blockIdx.x * 256 + threadIdx.x;
    if (i >= n) return;
    int excl = boff[blockIdx.x] + partial[i] - deg[i];
    rowptr[i] = excl;
    cursor[i] = excl;
    dinv[i] = rsqrtf((float)(deg[i] + 1));   // +1 = self loop
    if (i == 0) rowptr[n] = e;
}

// ---------------- CSR fill (by dst) ----------------
__global__ void k_fill(const int* __restrict__ src, const int* __restrict__ dst,
                       int* __restrict__ cursor, int* __restrict__ csr_src, int e) {
    int i = blockIdx.x * blockDim.x + threadIdx.x;
    if (i < e) {
        int p = atomicAdd(&cursor[dst[i]], 1);
        csr_src[p] = src[i];
    }
}

// ---------------- GEMM1: hs[i][f] = bf16( dinv[i] * sum_k x[i][k]*W1[f][k] ) ----------------
// BM=128 nodes, BN=128 (all f), BK=32. 256 threads, 8x8 register tile each.
#define BM 128
#define BK 32
__global__ __launch_bounds__(256) void k_gemm(const float* __restrict__ x, const float* __restrict__ W1,
                                              const float* __restrict__ dinv,
                                              unsigned short* __restrict__ hs, int n) {
    __shared__ float xs[BK][BM + 4];   // [kk][m], 16.9 KB
    __shared__ float ws[BK][HID];      // [kk][f], 16 KB
    const int tid = threadIdx.x;
    const int i0 = blockIdx.x * BM;
    const int m0 = (tid >> 4) << 3;    // 0..120
    const int f0 = (tid & 15) << 3;    // 0..120
    float acc[8][8] = {};

    const int srow = tid & 127;
    const int scg  = (tid >> 7) << 4;  // 0 or 16

    for (int kb = 0; kb < FIN; kb += BK) {
        // stage x tile: 128 rows x 32 k
        {
            int gi = i0 + srow;
            const float* xp = &x[(size_t)gi * FIN + kb + scg];
            #pragma unroll
            for (int j = 0; j < 16; j += 4) {
                float4 v = {0.f, 0.f, 0.f, 0.f};
                if (gi < n) v = *(const float4*)&xp[j];
                xs[scg + j + 0][srow] = v.x; xs[scg + j + 1][srow] = v.y;
                xs[scg + j + 2][srow] = v.z; xs[scg + j + 3][srow] = v.w;
            }
        }
        // stage W tile: 128 f x 32 k
        {
            const float* wp = &W1[(size_t)srow * FIN + kb + scg];
            #pragma unroll
            for (int j = 0; j < 16; j += 4) {
                float4 v = *(const float4*)&wp[j];
                ws[scg + j + 0][srow] = v.x; ws[scg + j + 1][srow] = v.y;
                ws[scg + j + 2][srow] = v.z; ws[scg + j + 3][srow] = v.w;
            }
        }
        __syncthreads();
        #pragma unroll
        for (int kk = 0; kk < BK; ++kk) {
            float a[8], b[8];
            *(float4*)&a[0] = *(const float4*)&xs[kk][m0];
            *(float4*)&a[4] = *(const float4*)&xs[kk][m0 + 4];
            *(float4*)&b[0] = *(const float4*)&ws[kk][f0];
            *(float4*)&b[4] = *(const float4*)&ws[kk][f0 + 4];
            #pragma unroll
            for (int ii = 0; ii < 8; ++ii)
                #pragma unroll
                for (int jj = 0; jj < 8; ++jj)
                    acc[ii][jj] += a[ii] * b[jj];
        }
        __syncthreads();
    }
    #pragma unroll
    for (int ii = 0; ii < 8; ++ii) {
        int gi = i0 + m0 + ii;
        if (gi < n) {
            float di = dinv[gi];
            ushort8v o;
            #pragma unroll
            for (int jj = 0; jj < 8; ++jj) o[jj] = f2bf(acc[ii][jj] * di);
            *(ushort8v*)&hs[(size_t)gi * HID + f0] = o;
        }
    }
}

// ---------------- layer-1 aggregation fused with layer-2 dot ----------------
// one wave per node; hs rows are bf16 (lane owns features 2*lane, 2*lane+1)
__global__ __launch_bounds__(256) void k_agg1(const unsigned int* __restrict__ hs,
                                              const int* __restrict__ rowptr,
                                              const int* __restrict__ csr_src,
                                              const float* __restrict__ dinv,
                                              const float* __restrict__ b1, const float* __restrict__ W2,
                                              float* __restrict__ zs, int n) {
    int i = (blockIdx.x << 2) + (threadIdx.x >> 6);
    if (i >= n) return;
    const int lane = threadIdx.x & 63;

    unsigned int sv = hs[(i << 6) + lane];                 // self-loop term
    float ax = __uint_as_float(sv << 16);
    float ay = __uint_as_float(sv & 0xffff0000u);

    int e = rowptr[i];
    const int end = rowptr[i + 1];
    while (e < end) {
        int cnt = end - e;
        if (cnt > 64) cnt = 64;
        int sidx = (lane < cnt) ? csr_src[e + lane] : 0;
        int j = 0;
        for (; j + 2 <= cnt; j += 2) {
            int s0 = __shfl(sidx, j, 64);
            int s1 = __shfl(sidx, j + 1, 64);
            unsigned int v0 = hs[(s0 << 6) + lane];
            unsigned int v1 = hs[(s1 << 6) + lane];
            ax += __uint_as_float(v0 << 16);
            ay += __uint_as_float(v0 & 0xffff0000u);
            ax += __uint_as_float(v1 << 16);
            ay += __uint_as_float(v1 & 0xffff0000u);
        }
        if (j < cnt) {
            int s0 = __shfl(sidx, j, 64);
            unsigned int v0 = hs[(s0 << 6) + lane];
            ax += __uint_as_float(v0 << 16);
            ay += __uint_as_float(v0 & 0xffff0000u);
        }
        e += cnt;
    }
    float di = dinv[i];
    float2 bb = ((const float2*)b1)[lane];
    float h0 = fmaxf(ax * di + bb.x, 0.f);
    float h1 = fmaxf(ay * di + bb.y, 0.f);
    float2 w2 = ((const float2*)W2)[lane];
    float z = h0 * w2.x + h1 * w2.y;
    #pragma unroll
    for (int off = 32; off; off >>= 1) z += __shfl_xor(z, off, 64);
    if (lane == 0) zs[i] = z * di;
}

// ---------------- layer-2 aggregation ----------------
__global__ void k_agg2(const float* __restrict__ zs, const int* __restrict__ rowptr,
                       const int* __restrict__ csr_src, const float* __restrict__ dinv,
                       const float* __restrict__ b2, float* __restrict__ out, int n) {
    int i = blockIdx.x * blockDim.x + threadIdx.x;
    if (i >= n) return;
    float acc = zs[i];
    int beg = rowptr[i], end = rowptr[i + 1];
    for (int e = beg; e < end; ++e) acc += zs[csr_src[e]];
    out[i] = acc * dinv[i] + b2[0];
}

extern "C" void kernel_launch(void* const* d_in, const int* in_sizes, int n_in,
                              void* d_out, int out_size, void* d_ws, size_t ws_size,
                              hipStream_t stream) {
    const float* x  = (const float*)d_in[0];
    const int*   ei = (const int*)d_in[1];
    const float* W1 = (const float*)d_in[2];
    const float* b1 = (const float*)d_in[3];
    const float* W2 = (const float*)d_in[4];
    const float* b2 = (const float*)d_in[5];
    float* out = (float*)d_out;

    const int n = in_sizes[0] / FIN;
    const int e = in_sizes[1] / 2;
    const int* src = ei;
    const int* dst = ei + e;

    char* p = (char*)d_ws;
    auto carve = [&](size_t bytes) { char* q = p; p += (bytes + 255) & ~(size_t)255; return q; };
    int*            deg     = (int*)carve((size_t)n * 4);
    int*            partial = (int*)carve((size_t)n * 4);
    int*            bsum    = (int*)carve(4096);
    int*            boff    = (int*)carve(4096);
    int*            rowptr  = (int*)carve((size_t)(n + 1) * 4);
    int*            cursor  = (int*)carve((size_t)n * 4);
    float*          dinv    = (float*)carve((size_t)n * 4);
    int*            csr     = (int*)carve((size_t)e * 4);
    unsigned short* hs      = (unsigned short*)carve((size_t)n * HID * 2);
    float*          zs      = (float*)carve((size_t)n * 4);

    hipMemsetAsync(deg, 0, (size_t)n * 4, stream);

    const int nb = (n + 255) / 256;
    k_deg  <<<(e + 255) / 256, 256, 0, stream>>>(dst, deg, e);
    k_scan1<<<nb, 256, 0, stream>>>(deg, partial, bsum, n);
    k_scan2<<<1, 512, 0, stream>>>(bsum, boff, nb);
    k_scan3<<<nb, 256, 0, stream>>>(deg, partial, boff, rowptr, cursor, dinv, n, e);
    k_fill <<<(e + 255) / 256, 256, 0, stream>>>(src, dst, cursor, csr, e);
    k_gemm <<<(n + BM - 1) / BM, 256, 0, stream>>>(x, W1, dinv, hs, n);
    k_agg1 <<<(n + 3) / 4, 256, 0, stream>>>((const unsigned int*)hs, rowptr, csr, dinv, b1, W2, zs, n);
    k_agg2 <<<(n + 255) / 256, 256, 0, stream>>>(zs, rowptr, csr, dinv, b2, out, n);
}